// Round 8
// baseline (40.953 us; speedup 1.0000x reference)
//
#include <hip/hip_runtime.h>

// PullbackMetric, 8 threads/pixel (thread r owns row r of all 8x8 matrices).
// G[m][n] = dmu_m^T Si dmu_n + 0.5 tr( (Si dSig_m)(Si dSig_n) )
// Using Si = Si^T:  X = dSx*Si, Y = dSy*Si (row r = dot(own dS row, Si rows)).
//   cov00 = sum_ik X[i,k]X[k,i]; cov01 = sum_ik Y[i,k]X[k,i]; cov11 analog.
// Si staged once per pixel in LDS (only LDS use, one barrier, conflict-free by
// construction). Column slices X[k][r] obtained by in-register Eklundh 8x8
// transpose across the 8 lanes (shfl_xor 1,2,4). Mean term row-parallel via
// v = Si*dmu. Raw diffs (no 0.5): folded into final 0.25/0.125 scale.

constexpr int SSTRIDE = 68;   // floats per pixel slot (272 B, 16B-aligned)

// Eklundh stage: exchange element pairs across lanes r <-> r^m, regs k <-> k|m.
#define XSTEP(M, mmask)                                              \
    _Pragma("unroll")                                                \
    for (int k_ = 0; k_ < 8; ++k_) {                                 \
        if ((k_ & (mmask)) == 0) {                                   \
            const int k2_ = k_ | (mmask);                            \
            float give_ = (r & (mmask)) ? M[k_] : M[k2_];            \
            float got_  = __shfl_xor(give_, (mmask));                \
            M[k_]  = (r & (mmask)) ? got_  : M[k_];                  \
            M[k2_] = (r & (mmask)) ? M[k2_] : got_;                  \
        }                                                            \
    }

__global__ __launch_bounds__(256, 6) void pm8_kernel(
    const float* __restrict__ mu,
    const float* __restrict__ sigma,
    const float* __restrict__ sigma_inv,
    float* __restrict__ out)
{
    __shared__ float mS[32 * SSTRIDE];   // 8704 B: Si, 32 pixels/block

    const int tid = threadIdx.x;
    const int r   = tid & 7;     // matrix row owned by this thread
    const int p   = tid >> 3;    // pixel within block (0..31)

    // XCD-aware chunked swizzle: 8192 blocks, 8 XCDs, 1024 contiguous/XCD
    const int bid = blockIdx.x;
    const int swz = (bid & 7) * 1024 + (bid >> 3);
    const int idx = swz * 32 + p;          // pixel 0..262143

    const int x = idx >> 9, y = idx & 511;
    const int ixp = (((x + 1) & 511) << 9) | y;
    const int ixm = (((x - 1) & 511) << 9) | y;
    const int iyp = (x << 9) | ((y + 1) & 511);
    const int iym = (x << 9) | ((y - 1) & 511);

    float* slot = mS + p * SSTRIDE;

    // ---------------- Si row r: load, stage to LDS, keep in regs ----------------
    float sirow[8];
    {
        const float4* q = reinterpret_cast<const float4*>(sigma_inv + (size_t)idx * 64 + r * 8);
        float4 s0 = q[0], s1 = q[1];
        sirow[0] = s0.x; sirow[1] = s0.y; sirow[2] = s0.z; sirow[3] = s0.w;
        sirow[4] = s1.x; sirow[5] = s1.y; sirow[6] = s1.z; sirow[7] = s1.w;
        float4* w = reinterpret_cast<float4*>(slot + r * 8);
        w[0] = s0; w[1] = s1;
    }

    // ---------------- raw dS rows (no 0.5 factor) ----------------
    float dsx[8], dsy[8];
    {
        const float4* a = reinterpret_cast<const float4*>(sigma + (size_t)ixp * 64 + r * 8);
        const float4* b = reinterpret_cast<const float4*>(sigma + (size_t)ixm * 64 + r * 8);
        float4 a0 = a[0], a1 = a[1], b0 = b[0], b1 = b[1];
        dsx[0] = a0.x - b0.x; dsx[1] = a0.y - b0.y; dsx[2] = a0.z - b0.z; dsx[3] = a0.w - b0.w;
        dsx[4] = a1.x - b1.x; dsx[5] = a1.y - b1.y; dsx[6] = a1.z - b1.z; dsx[7] = a1.w - b1.w;
    }
    {
        const float4* a = reinterpret_cast<const float4*>(sigma + (size_t)iyp * 64 + r * 8);
        const float4* b = reinterpret_cast<const float4*>(sigma + (size_t)iym * 64 + r * 8);
        float4 a0 = a[0], a1 = a[1], b0 = b[0], b1 = b[1];
        dsy[0] = a0.x - b0.x; dsy[1] = a0.y - b0.y; dsy[2] = a0.z - b0.z; dsy[3] = a0.w - b0.w;
        dsy[4] = a1.x - b1.x; dsy[5] = a1.y - b1.y; dsy[6] = a1.z - b1.z; dsy[7] = a1.w - b1.w;
    }

    // ---------------- mean term, row-parallel ----------------
    // raw dmu vectors (x8 redundant loads, but same-address -> coalescer dedups)
    float v0r = 0.f, v1r = 0.f;   // (Si * dmu0)[r], (Si * dmu1)[r]  (raw scale)
    float d0r, d1r;               // dmu0[r], dmu1[r] (raw scale, own component)
    {
        const float4* mxp = reinterpret_cast<const float4*>(mu + (size_t)ixp * 8);
        const float4* mxm = reinterpret_cast<const float4*>(mu + (size_t)ixm * 8);
        const float4* myp = reinterpret_cast<const float4*>(mu + (size_t)iyp * 8);
        const float4* mym = reinterpret_cast<const float4*>(mu + (size_t)iym * 8);
        float dmu0[8], dmu1[8];
        {
            float4 a0 = mxp[0], a1 = mxp[1], b0 = mxm[0], b1 = mxm[1];
            dmu0[0] = a0.x - b0.x; dmu0[1] = a0.y - b0.y; dmu0[2] = a0.z - b0.z; dmu0[3] = a0.w - b0.w;
            dmu0[4] = a1.x - b1.x; dmu0[5] = a1.y - b1.y; dmu0[6] = a1.z - b1.z; dmu0[7] = a1.w - b1.w;
            float4 c0 = myp[0], c1 = myp[1], d0 = mym[0], d1 = mym[1];
            dmu1[0] = c0.x - d0.x; dmu1[1] = c0.y - d0.y; dmu1[2] = c0.z - d0.z; dmu1[3] = c0.w - d0.w;
            dmu1[4] = c1.x - d1.x; dmu1[5] = c1.y - d1.y; dmu1[6] = c1.z - d1.z; dmu1[7] = c1.w - d1.w;
        }
        #pragma unroll
        for (int j = 0; j < 8; ++j) {
            v0r = fmaf(sirow[j], dmu0[j], v0r);
            v1r = fmaf(sirow[j], dmu1[j], v1r);
        }
        // own components (compile-time unrolled select -> cndmask, no scratch)
        d0r = dmu0[0]; d1r = dmu1[0];
        #pragma unroll
        for (int c = 1; c < 8; ++c) {
            if (r == c) { d0r = dmu0[c]; d1r = dmu1[c]; }
        }
    }

    __syncthreads();   // Si staged (the only barrier)

    // ---------------- X,Y rows: stream Si rows from LDS (8-lane broadcast) ----------------
    // X[k] = dot(dsx, Si_row_k) = X[r][k] via Si symmetry; same for Y.
    float X[8], Y[8];
    #pragma unroll
    for (int k = 0; k < 8; ++k) {
        float row[8];
        *reinterpret_cast<float4*>(&row[0]) = *reinterpret_cast<const float4*>(slot + k * 8);
        *reinterpret_cast<float4*>(&row[4]) = *reinterpret_cast<const float4*>(slot + k * 8 + 4);
        float xa = 0.f, ya = 0.f;
        #pragma unroll
        for (int j = 0; j < 8; ++j) {
            xa = fmaf(dsx[j], row[j], xa);
            ya = fmaf(dsy[j], row[j], ya);
        }
        X[k] = xa; Y[k] = ya;
    }

    // ---------------- in-register 8x8 transpose across the 8 lanes ----------------
    float XT[8], YT[8];
    #pragma unroll
    for (int k = 0; k < 8; ++k) { XT[k] = X[k]; YT[k] = Y[k]; }
    XSTEP(XT, 1) XSTEP(XT, 2) XSTEP(XT, 4)   // XT[k] = X[k][r]
    XSTEP(YT, 1) XSTEP(YT, 2) XSTEP(YT, 4)   // YT[k] = Y[k][r]

    // ---------------- cov partials (row r) ----------------
    float c00 = 0.f, c01 = 0.f, c11 = 0.f;
    #pragma unroll
    for (int k = 0; k < 8; ++k) {
        c00 = fmaf(X[k], XT[k], c00);   // X[r,k] X[k,r]
        c01 = fmaf(Y[k], XT[k], c01);   // Y[r,k] X[k,r]  (== tr(XY) after full sum)
        c11 = fmaf(Y[k], YT[k], c11);   // Y[r,k] Y[k,r]
    }
    float mp0 = d0r * v0r;   // dmu0[r] * (Si dmu0)[r]
    float mp1 = d0r * v1r;
    float mp2 = d1r * v1r;

    // ---------------- reduce over the 8 lanes ----------------
    #pragma unroll
    for (int m = 1; m < 8; m <<= 1) {
        c00 += __shfl_xor(c00, m);
        c01 += __shfl_xor(c01, m);
        c11 += __shfl_xor(c11, m);
        mp0 += __shfl_xor(mp0, m);
        mp1 += __shfl_xor(mp1, m);
        mp2 += __shfl_xor(mp2, m);
    }

    // ---------------- combine (fold the two 0.5 FD factors) and write ----------------
    if (r == 0) {
        float4 g;
        g.x = 0.25f * mp0 + 0.125f * c00;   // G[0][0]
        g.y = 0.25f * mp1 + 0.125f * c01;   // G[0][1]
        g.z = g.y;                          // G[1][0]
        g.w = 0.25f * mp2 + 0.125f * c11;   // G[1][1]
        reinterpret_cast<float4*>(out)[idx] = g;
    }
}

extern "C" void kernel_launch(void* const* d_in, const int* in_sizes, int n_in,
                              void* d_out, int out_size, void* d_ws, size_t ws_size,
                              hipStream_t stream) {
    const float* mu        = (const float*)d_in[0];
    const float* sigma     = (const float*)d_in[1];
    const float* sigma_inv = (const float*)d_in[2];
    float* out = (float*)d_out;

    // 262144 pixels * 8 threads / 256 = 8192 blocks (divisible by 8 -> bijective swizzle)
    pm8_kernel<<<8192, 256, 0, stream>>>(mu, sigma, sigma_inv, out);
}

// Round 9
// 39.150 us; speedup vs baseline: 1.0460x; 1.0460x over previous
//
#include <hip/hip_runtime.h>

// PullbackMetric, 4 threads/pixel (thread s owns rows {2s,2s+1}).
// G[m][n] = dmu_m^T Si dmu_n + 0.5 tr( (Si dSig_m)(Si dSig_n) )
// Si = Si^T, dSig symmetric. X = dSx*Si, Y = dSy*Si (rows from register dS rows
// dotted with Si rows streamed from LDS; Si staged once per pixel = only staging).
// cov00 = sum X[i,k]X[k,i] etc: transpose via 2-stage Eklundh shfl across the
// 4 quad lanes (blocks of 2x2), zero extra LDS, zero extra barriers.
// dmu staged cooperatively (1 f4 per thread). Raw diffs; 0.5s folded into 0.25/0.125.
// Tripwire: if WRITE_SIZE >> 4 MB, registers spilled -> revert to R4+Eklundh.

constexpr int SSTRIDE = 68;   // Si slot stride (272 B, 16B-aligned)
constexpr int DSTRIDE = 20;   // dmu slot stride (80 B)

// One Eklundh stage (mask M in {1,2}) on a matrix held as 4 lanes x 2 row-arrays.
// Exchanges 2x2 blocks (s,b) <-> (s^M, b^M) where (s^b)&M != 0. Safe in-place.
#define TSTEP(S0, S1, D0, D1, M)                                         \
    _Pragma("unroll")                                                    \
    for (int j_ = 0; j_ < 8; ++j_) {                                     \
        if ((j_ & (2*(M))) == 0) {                                       \
            const int j2_ = j_ | (2*(M));                                \
            const bool a_ = ((s ^ (j_ >> 1)) & (M)) != 0;                \
            float g0_ = a_ ? S0[j_] : S0[j2_];                           \
            float g1_ = a_ ? S1[j_] : S1[j2_];                           \
            float r0_ = __shfl_xor(g0_, (M));                            \
            float r1_ = __shfl_xor(g1_, (M));                            \
            D0[j_]  = a_ ? r0_ : S0[j_];   D0[j2_] = a_ ? S0[j2_] : r0_; \
            D1[j_]  = a_ ? r1_ : S1[j_];   D1[j2_] = a_ ? S1[j2_] : r1_; \
        }                                                                \
    }

__global__ __launch_bounds__(256, 4) void pm9_kernel(
    const float* __restrict__ mu,
    const float* __restrict__ sigma,
    const float* __restrict__ sigma_inv,
    float* __restrict__ out)
{
    __shared__ float mS[64 * SSTRIDE];   // Si: 17408 B
    __shared__ float mD[64 * DSTRIDE];   // dmu: 5120 B  (22528 B total)

    const int tid = threadIdx.x;
    const int s   = tid & 3;     // row-pair id
    const int p   = tid >> 2;    // pixel within block (0..63)

    // XCD-aware chunked swizzle: 4096 blocks = 8 XCDs x 512
    const int bid = blockIdx.x;
    const int swz = (bid & 7) * 512 + (bid >> 3);
    const int idx = swz * 64 + p;

    const int x = idx >> 9, y = idx & 511;
    const int ixp = (((x + 1) & 511) << 9) | y;
    const int ixm = (((x - 1) & 511) << 9) | y;
    const int iyp = (x << 9) | ((y + 1) & 511);
    const int iym = (x << 9) | ((y - 1) & 511);

    float* slotS = mS + p * SSTRIDE;
    float* slotD = mD + p * DSTRIDE;

    // ---------------- Si rows 2s,2s+1: load, stage, keep ----------------
    float si0[8], si1[8];
    {
        const float4* q = reinterpret_cast<const float4*>(sigma_inv + (size_t)idx * 64 + s * 16);
        float4 q0 = q[0], q1 = q[1], q2 = q[2], q3 = q[3];
        si0[0]=q0.x; si0[1]=q0.y; si0[2]=q0.z; si0[3]=q0.w;
        si0[4]=q1.x; si0[5]=q1.y; si0[6]=q1.z; si0[7]=q1.w;
        si1[0]=q2.x; si1[1]=q2.y; si1[2]=q2.z; si1[3]=q2.w;
        si1[4]=q3.x; si1[5]=q3.y; si1[6]=q3.z; si1[7]=q3.w;
        float4* w = reinterpret_cast<float4*>(slotS + s * 16);
        w[0] = q0; w[1] = q1; w[2] = q2; w[3] = q3;
    }

    // ---------------- cooperative raw dmu quarter (1 f4 per thread) ----------------
    // slotD layout: [dmu0 raw (8) | dmu1 raw (8)]
    {
        const int plus  = (s < 2) ? ixp : iyp;
        const int minus = (s < 2) ? ixm : iym;
        const int h     = (s & 1) * 4;
        float4 a = *reinterpret_cast<const float4*>(mu + (size_t)plus  * 8 + h);
        float4 b = *reinterpret_cast<const float4*>(mu + (size_t)minus * 8 + h);
        float4 d;
        d.x = a.x - b.x; d.y = a.y - b.y; d.z = a.z - b.z; d.w = a.w - b.w;
        *reinterpret_cast<float4*>(slotD + s * 4) = d;
    }

    // ---------------- raw dS rows 2s,2s+1 (registers, no staging) ----------------
    float dsx0[8], dsx1[8], dsy0[8], dsy1[8];
    {
        const float4* a = reinterpret_cast<const float4*>(sigma + (size_t)ixp * 64 + s * 16);
        const float4* b = reinterpret_cast<const float4*>(sigma + (size_t)ixm * 64 + s * 16);
        float4 a0=a[0],a1=a[1],a2=a[2],a3=a[3], b0=b[0],b1=b[1],b2=b[2],b3=b[3];
        dsx0[0]=a0.x-b0.x; dsx0[1]=a0.y-b0.y; dsx0[2]=a0.z-b0.z; dsx0[3]=a0.w-b0.w;
        dsx0[4]=a1.x-b1.x; dsx0[5]=a1.y-b1.y; dsx0[6]=a1.z-b1.z; dsx0[7]=a1.w-b1.w;
        dsx1[0]=a2.x-b2.x; dsx1[1]=a2.y-b2.y; dsx1[2]=a2.z-b2.z; dsx1[3]=a2.w-b2.w;
        dsx1[4]=a3.x-b3.x; dsx1[5]=a3.y-b3.y; dsx1[6]=a3.z-b3.z; dsx1[7]=a3.w-b3.w;
    }
    {
        const float4* a = reinterpret_cast<const float4*>(sigma + (size_t)iyp * 64 + s * 16);
        const float4* b = reinterpret_cast<const float4*>(sigma + (size_t)iym * 64 + s * 16);
        float4 a0=a[0],a1=a[1],a2=a[2],a3=a[3], b0=b[0],b1=b[1],b2=b[2],b3=b[3];
        dsy0[0]=a0.x-b0.x; dsy0[1]=a0.y-b0.y; dsy0[2]=a0.z-b0.z; dsy0[3]=a0.w-b0.w;
        dsy0[4]=a1.x-b1.x; dsy0[5]=a1.y-b1.y; dsy0[6]=a1.z-b1.z; dsy0[7]=a1.w-b1.w;
        dsy1[0]=a2.x-b2.x; dsy1[1]=a2.y-b2.y; dsy1[2]=a2.z-b2.z; dsy1[3]=a2.w-b2.w;
        dsy1[4]=a3.x-b3.x; dsy1[5]=a3.y-b3.y; dsy1[6]=a3.z-b3.z; dsy1[7]=a3.w-b3.w;
    }

    __syncthreads();   // Si + dmu staged (the only barrier)

    // ---------------- mean term (non-redundant, uses kept Si rows) ----------------
    float mp0, mp1, mp2;
    {
        float dm0[8], dm1[8];
        *reinterpret_cast<float4*>(&dm0[0]) = *reinterpret_cast<const float4*>(slotD + 0);
        *reinterpret_cast<float4*>(&dm0[4]) = *reinterpret_cast<const float4*>(slotD + 4);
        *reinterpret_cast<float4*>(&dm1[0]) = *reinterpret_cast<const float4*>(slotD + 8);
        *reinterpret_cast<float4*>(&dm1[4]) = *reinterpret_cast<const float4*>(slotD + 12);
        float2 d0p = *reinterpret_cast<const float2*>(slotD + 2 * s);        // dmu0[2s],[2s+1]
        float2 d1p = *reinterpret_cast<const float2*>(slotD + 8 + 2 * s);    // dmu1[2s],[2s+1]
        float v00 = 0.f, v01 = 0.f, v10 = 0.f, v11 = 0.f;
        #pragma unroll
        for (int j = 0; j < 8; ++j) {
            v00 = fmaf(si0[j], dm0[j], v00);   // (Si dmu0)[2s]
            v01 = fmaf(si0[j], dm1[j], v01);   // (Si dmu1)[2s]
            v10 = fmaf(si1[j], dm0[j], v10);   // (Si dmu0)[2s+1]
            v11 = fmaf(si1[j], dm1[j], v11);   // (Si dmu1)[2s+1]
        }
        mp0 = d0p.x * v00 + d0p.y * v10;
        mp1 = d0p.x * v01 + d0p.y * v11;
        mp2 = d1p.x * v01 + d1p.y * v11;
    }

    // ---------------- X,Y rows: stream Si rows from LDS (quad-broadcast) ----------------
    // X0[k] = X[2s][k] = dot(dsx row 2s, Si row k)  (Si symmetric)
    float X0[8], X1[8], Y0[8], Y1[8];
    #pragma unroll
    for (int k = 0; k < 8; ++k) {
        float row[8];
        *reinterpret_cast<float4*>(&row[0]) = *reinterpret_cast<const float4*>(slotS + k * 8);
        *reinterpret_cast<float4*>(&row[4]) = *reinterpret_cast<const float4*>(slotS + k * 8 + 4);
        float x0 = 0.f, x1 = 0.f, y0 = 0.f, y1 = 0.f;
        #pragma unroll
        for (int j = 0; j < 8; ++j) {
            x0 = fmaf(dsx0[j], row[j], x0);
            x1 = fmaf(dsx1[j], row[j], x1);
            y0 = fmaf(dsy0[j], row[j], y0);
            y1 = fmaf(dsy1[j], row[j], y1);
        }
        X0[k] = x0; X1[k] = x1; Y0[k] = y0; Y1[k] = y1;
    }

    // ---------------- 8x8 transpose across the quad (2-stage block Eklundh) ----------------
    float TX0[8], TX1[8], TY0[8], TY1[8];
    TSTEP(X0, X1, TX0, TX1, 1)        // stage 1: src -> dst (doubles as the copy)
    TSTEP(Y0, Y1, TY0, TY1, 1)
    TSTEP(TX0, TX1, TX0, TX1, 2)      // stage 2: in-place
    TSTEP(TY0, TY1, TY0, TY1, 2)
    // After stages, block (b) holds orig block (b,s); intra-block 2x2 transpose is
    // done by compile-time renaming in the cov loop below.

    // ---------------- cov partials ----------------
    float c00 = 0.f, c01 = 0.f, c11 = 0.f;
    #pragma unroll
    for (int k = 0; k < 8; ++k) {
        const float xt0 = (k & 1) ? TX1[k ^ 1] : TX0[k];       // X[k][2s]
        const float xt1 = (k & 1) ? TX1[k]     : TX0[k ^ 1];   // X[k][2s+1]
        const float yt0 = (k & 1) ? TY1[k ^ 1] : TY0[k];       // Y[k][2s]
        const float yt1 = (k & 1) ? TY1[k]     : TY0[k ^ 1];   // Y[k][2s+1]
        c00 = fmaf(X0[k], xt0, c00); c00 = fmaf(X1[k], xt1, c00);
        c01 = fmaf(Y0[k], xt0, c01); c01 = fmaf(Y1[k], xt1, c01);
        c11 = fmaf(Y0[k], yt0, c11); c11 = fmaf(Y1[k], yt1, c11);
    }

    // ---------------- combine (fold FD 0.5s), quad-reduce, write ----------------
    float g0 = 0.25f * mp0 + 0.125f * c00;   // G[0][0]
    float g1 = 0.25f * mp1 + 0.125f * c01;   // G[0][1] == G[1][0]
    float g3 = 0.25f * mp2 + 0.125f * c11;   // G[1][1]
    g0 += __shfl_xor(g0, 1); g0 += __shfl_xor(g0, 2);
    g1 += __shfl_xor(g1, 1); g1 += __shfl_xor(g1, 2);
    g3 += __shfl_xor(g3, 1); g3 += __shfl_xor(g3, 2);

    float val = (s == 0) ? g0 : ((s == 3) ? g3 : g1);
    out[(size_t)idx * 4 + s] = val;
}

extern "C" void kernel_launch(void* const* d_in, const int* in_sizes, int n_in,
                              void* d_out, int out_size, void* d_ws, size_t ws_size,
                              hipStream_t stream) {
    const float* mu        = (const float*)d_in[0];
    const float* sigma     = (const float*)d_in[1];
    const float* sigma_inv = (const float*)d_in[2];
    float* out = (float*)d_out;

    // 262144 pixels * 4 threads / 256 = 4096 blocks (divisible by 8 -> bijective swizzle)
    pm9_kernel<<<4096, 256, 0, stream>>>(mu, sigma, sigma_inv, out);
}

// Round 10
// 32.173 us; speedup vs baseline: 1.2729x; 1.2169x over previous
//
#include <hip/hip_runtime.h>

// PullbackMetric, 4 threads/pixel (thread s owns rows {2s,2s+1}).
// G[m][n] = dmu_m^T Si dmu_n + 0.5 tr( (Si dSig_m)(Si dSig_n) )
// Si = Si^T, dSig symmetric. X = dSx*Si, Y = dSy*Si rows from register dS rows
// dotted with Si rows streamed (broadcast) from LDS; Si staged once per pixel.
// cov traces via 2-stage Eklundh shfl transpose across the quad (DPP, no LDS).
// R10 = R9 with sequential X->Y phases (halves peak live regs) + bounds (256,3)
// to kill the 64-VGPR spill seen in R5/R7/R9 (WRITE_SIZE tripwire).

constexpr int SSTRIDE = 68;   // Si slot stride (272 B, 16B-aligned)
constexpr int DSTRIDE = 20;   // dmu slot stride (80 B)

// One Eklundh stage (mask M in {1,2}) on a matrix held as 4 lanes x 2 row-arrays.
// Exchanges 2x2 blocks (s,b) <-> (s^M, b^M) where (s^b)&M != 0. D may alias S.
#define TSTEP(S0, S1, D0, D1, M)                                         \
    _Pragma("unroll")                                                    \
    for (int j_ = 0; j_ < 8; ++j_) {                                     \
        if ((j_ & (2*(M))) == 0) {                                       \
            const int j2_ = j_ | (2*(M));                                \
            const bool a_ = ((s ^ (j_ >> 1)) & (M)) != 0;                \
            float g0_ = a_ ? S0[j_] : S0[j2_];                           \
            float g1_ = a_ ? S1[j_] : S1[j2_];                           \
            float r0_ = __shfl_xor(g0_, (M));                            \
            float r1_ = __shfl_xor(g1_, (M));                            \
            D0[j_]  = a_ ? r0_ : S0[j_];   D0[j2_] = a_ ? S0[j2_] : r0_; \
            D1[j_]  = a_ ? r1_ : S1[j_];   D1[j2_] = a_ ? S1[j2_] : r1_; \
        }                                                                \
    }

__global__ __launch_bounds__(256, 3) void pm10_kernel(
    const float* __restrict__ mu,
    const float* __restrict__ sigma,
    const float* __restrict__ sigma_inv,
    float* __restrict__ out)
{
    __shared__ float mS[64 * SSTRIDE];   // Si: 17408 B
    __shared__ float mD[64 * DSTRIDE];   // dmu: 5120 B  (22528 B total)

    const int tid = threadIdx.x;
    const int s   = tid & 3;     // row-pair id
    const int p   = tid >> 2;    // pixel within block (0..63)

    // XCD-aware chunked swizzle: 4096 blocks = 8 XCDs x 512
    const int bid = blockIdx.x;
    const int swz = (bid & 7) * 512 + (bid >> 3);
    const int idx = swz * 64 + p;

    const int x = idx >> 9, y = idx & 511;
    const int ixp = (((x + 1) & 511) << 9) | y;
    const int ixm = (((x - 1) & 511) << 9) | y;
    const int iyp = (x << 9) | ((y + 1) & 511);
    const int iym = (x << 9) | ((y - 1) & 511);

    float* slotS = mS + p * SSTRIDE;
    float* slotD = mD + p * DSTRIDE;

    // ---------------- Si rows 2s,2s+1: load, stage, keep ----------------
    float si0[8], si1[8];
    {
        const float4* q = reinterpret_cast<const float4*>(sigma_inv + (size_t)idx * 64 + s * 16);
        float4 q0 = q[0], q1 = q[1], q2 = q[2], q3 = q[3];
        si0[0]=q0.x; si0[1]=q0.y; si0[2]=q0.z; si0[3]=q0.w;
        si0[4]=q1.x; si0[5]=q1.y; si0[6]=q1.z; si0[7]=q1.w;
        si1[0]=q2.x; si1[1]=q2.y; si1[2]=q2.z; si1[3]=q2.w;
        si1[4]=q3.x; si1[5]=q3.y; si1[6]=q3.z; si1[7]=q3.w;
        float4* w = reinterpret_cast<float4*>(slotS + s * 16);
        w[0] = q0; w[1] = q1; w[2] = q2; w[3] = q3;
    }

    // ---------------- cooperative raw dmu quarter (1 f4 per thread) ----------------
    // slotD layout: [dmu0 raw (8) | dmu1 raw (8)]
    {
        const int plus  = (s < 2) ? ixp : iyp;
        const int minus = (s < 2) ? ixm : iym;
        const int h     = (s & 1) * 4;
        float4 a = *reinterpret_cast<const float4*>(mu + (size_t)plus  * 8 + h);
        float4 b = *reinterpret_cast<const float4*>(mu + (size_t)minus * 8 + h);
        float4 d;
        d.x = a.x - b.x; d.y = a.y - b.y; d.z = a.z - b.z; d.w = a.w - b.w;
        *reinterpret_cast<float4*>(slotD + s * 4) = d;
    }

    // ---------------- raw dS rows 2s,2s+1 (registers, no staging) ----------------
    float dsx0[8], dsx1[8], dsy0[8], dsy1[8];
    {
        const float4* a = reinterpret_cast<const float4*>(sigma + (size_t)ixp * 64 + s * 16);
        const float4* b = reinterpret_cast<const float4*>(sigma + (size_t)ixm * 64 + s * 16);
        float4 a0=a[0],a1=a[1],a2=a[2],a3=a[3], b0=b[0],b1=b[1],b2=b[2],b3=b[3];
        dsx0[0]=a0.x-b0.x; dsx0[1]=a0.y-b0.y; dsx0[2]=a0.z-b0.z; dsx0[3]=a0.w-b0.w;
        dsx0[4]=a1.x-b1.x; dsx0[5]=a1.y-b1.y; dsx0[6]=a1.z-b1.z; dsx0[7]=a1.w-b1.w;
        dsx1[0]=a2.x-b2.x; dsx1[1]=a2.y-b2.y; dsx1[2]=a2.z-b2.z; dsx1[3]=a2.w-b2.w;
        dsx1[4]=a3.x-b3.x; dsx1[5]=a3.y-b3.y; dsx1[6]=a3.z-b3.z; dsx1[7]=a3.w-b3.w;
    }
    {
        const float4* a = reinterpret_cast<const float4*>(sigma + (size_t)iyp * 64 + s * 16);
        const float4* b = reinterpret_cast<const float4*>(sigma + (size_t)iym * 64 + s * 16);
        float4 a0=a[0],a1=a[1],a2=a[2],a3=a[3], b0=b[0],b1=b[1],b2=b[2],b3=b[3];
        dsy0[0]=a0.x-b0.x; dsy0[1]=a0.y-b0.y; dsy0[2]=a0.z-b0.z; dsy0[3]=a0.w-b0.w;
        dsy0[4]=a1.x-b1.x; dsy0[5]=a1.y-b1.y; dsy0[6]=a1.z-b1.z; dsy0[7]=a1.w-b1.w;
        dsy1[0]=a2.x-b2.x; dsy1[1]=a2.y-b2.y; dsy1[2]=a2.z-b2.z; dsy1[3]=a2.w-b2.w;
        dsy1[4]=a3.x-b3.x; dsy1[5]=a3.y-b3.y; dsy1[6]=a3.z-b3.z; dsy1[7]=a3.w-b3.w;
    }

    __syncthreads();   // Si + dmu staged (the only barrier)

    // ---------------- mean term (si rows die here) ----------------
    float mp0, mp1, mp2;
    {
        float dm0[8], dm1[8];
        *reinterpret_cast<float4*>(&dm0[0]) = *reinterpret_cast<const float4*>(slotD + 0);
        *reinterpret_cast<float4*>(&dm0[4]) = *reinterpret_cast<const float4*>(slotD + 4);
        *reinterpret_cast<float4*>(&dm1[0]) = *reinterpret_cast<const float4*>(slotD + 8);
        *reinterpret_cast<float4*>(&dm1[4]) = *reinterpret_cast<const float4*>(slotD + 12);
        // own components via compile-time unrolled select (no extra LDS reads)
        float d0a = dm0[0], d0b = dm0[1], d1a = dm1[0], d1b = dm1[1];
        #pragma unroll
        for (int c = 1; c < 4; ++c) {
            if (s == c) {
                d0a = dm0[2*c]; d0b = dm0[2*c+1];
                d1a = dm1[2*c]; d1b = dm1[2*c+1];
            }
        }
        float v00 = 0.f, v01 = 0.f, v10 = 0.f, v11 = 0.f;
        #pragma unroll
        for (int j = 0; j < 8; ++j) {
            v00 = fmaf(si0[j], dm0[j], v00);   // (Si dmu0)[2s]
            v01 = fmaf(si0[j], dm1[j], v01);   // (Si dmu1)[2s]
            v10 = fmaf(si1[j], dm0[j], v10);   // (Si dmu0)[2s+1]
            v11 = fmaf(si1[j], dm1[j], v11);   // (Si dmu1)[2s+1]
        }
        mp0 = d0a * v00 + d0b * v10;
        mp1 = d0a * v01 + d0b * v11;
        mp2 = d1a * v01 + d1b * v11;
    }

    // ---------------- phase X: stream Si, X rows, transpose, c00 ----------------
    float c00 = 0.f, c01 = 0.f, c11 = 0.f;
    float TX0[8], TX1[8];
    {
        float X0[8], X1[8];
        #pragma unroll
        for (int k = 0; k < 8; ++k) {
            float row[8];
            *reinterpret_cast<float4*>(&row[0]) = *reinterpret_cast<const float4*>(slotS + k * 8);
            *reinterpret_cast<float4*>(&row[4]) = *reinterpret_cast<const float4*>(slotS + k * 8 + 4);
            float x0 = 0.f, x1 = 0.f;
            #pragma unroll
            for (int j = 0; j < 8; ++j) {
                x0 = fmaf(dsx0[j], row[j], x0);
                x1 = fmaf(dsx1[j], row[j], x1);
            }
            X0[k] = x0; X1[k] = x1;   // X[2s][k], X[2s+1][k]
        }
        TSTEP(X0, X1, TX0, TX1, 1)       // stage 1 (copies into TX)
        TSTEP(TX0, TX1, TX0, TX1, 2)     // stage 2 in-place
        // c00 = sum_k X[2s,k] X[k,2s] + X[2s+1,k] X[k,2s+1]
        #pragma unroll
        for (int k = 0; k < 8; ++k) {
            const float xt0 = (k & 1) ? TX1[k ^ 1] : TX0[k];       // X[k][2s]
            const float xt1 = (k & 1) ? TX1[k]     : TX0[k ^ 1];   // X[k][2s+1]
            c00 = fmaf(X0[k], xt0, c00);
            c00 = fmaf(X1[k], xt1, c00);
        }
    }   // X0/X1, dsx dead

    // ---------------- phase Y: stream Si, Y rows, c01, transpose, c11 ----------------
    {
        float Y0[8], Y1[8];
        #pragma unroll
        for (int k = 0; k < 8; ++k) {
            float row[8];
            *reinterpret_cast<float4*>(&row[0]) = *reinterpret_cast<const float4*>(slotS + k * 8);
            *reinterpret_cast<float4*>(&row[4]) = *reinterpret_cast<const float4*>(slotS + k * 8 + 4);
            float y0 = 0.f, y1 = 0.f;
            #pragma unroll
            for (int j = 0; j < 8; ++j) {
                y0 = fmaf(dsy0[j], row[j], y0);
                y1 = fmaf(dsy1[j], row[j], y1);
            }
            Y0[k] = y0; Y1[k] = y1;
        }
        // c01 = sum_k Y[2s,k] X[k,2s] + Y[2s+1,k] X[k,2s+1]  (trace of X*Y)
        #pragma unroll
        for (int k = 0; k < 8; ++k) {
            const float xt0 = (k & 1) ? TX1[k ^ 1] : TX0[k];
            const float xt1 = (k & 1) ? TX1[k]     : TX0[k ^ 1];
            c01 = fmaf(Y0[k], xt0, c01);
            c01 = fmaf(Y1[k], xt1, c01);
        }   // TX dead
        float TY0[8], TY1[8];
        TSTEP(Y0, Y1, TY0, TY1, 1)
        TSTEP(TY0, TY1, TY0, TY1, 2)
        #pragma unroll
        for (int k = 0; k < 8; ++k) {
            const float yt0 = (k & 1) ? TY1[k ^ 1] : TY0[k];       // Y[k][2s]
            const float yt1 = (k & 1) ? TY1[k]     : TY0[k ^ 1];   // Y[k][2s+1]
            c11 = fmaf(Y0[k], yt0, c11);
            c11 = fmaf(Y1[k], yt1, c11);
        }
    }

    // ---------------- combine (fold FD 0.5s), quad-reduce, write ----------------
    float g0 = 0.25f * mp0 + 0.125f * c00;   // G[0][0]
    float g1 = 0.25f * mp1 + 0.125f * c01;   // G[0][1] == G[1][0]
    float g3 = 0.25f * mp2 + 0.125f * c11;   // G[1][1]
    g0 += __shfl_xor(g0, 1); g0 += __shfl_xor(g0, 2);
    g1 += __shfl_xor(g1, 1); g1 += __shfl_xor(g1, 2);
    g3 += __shfl_xor(g3, 1); g3 += __shfl_xor(g3, 2);

    float val = (s == 0) ? g0 : ((s == 3) ? g3 : g1);
    out[(size_t)idx * 4 + s] = val;
}

extern "C" void kernel_launch(void* const* d_in, const int* in_sizes, int n_in,
                              void* d_out, int out_size, void* d_ws, size_t ws_size,
                              hipStream_t stream) {
    const float* mu        = (const float*)d_in[0];
    const float* sigma     = (const float*)d_in[1];
    const float* sigma_inv = (const float*)d_in[2];
    float* out = (float*)d_out;

    // 262144 pixels * 4 threads / 256 = 4096 blocks (divisible by 8 -> bijective swizzle)
    pm10_kernel<<<4096, 256, 0, stream>>>(mu, sigma, sigma_inv, out);
}